// Round 1
// baseline (610.543 us; speedup 1.0000x reference)
//
#include <hip/hip_runtime.h>
#include <hip/hip_bf16.h>

// Fused 2-layer Elman RNN + FC head for MI355X (gfx950).
// B=16384, T=28, IN=28, H1=128, H2=64, NC=10. fp32 compute (no fp32 MFMA on
// CDNA4 -> vector ALU). Round 1: correctness-first baseline.
//
// Structure: 256 blocks x 256 threads. Block owns 64 batch elements fully
// (all timesteps, both layers, FC accumulation). Weights LDS-resident:
//   W_hh1^T fp32 [128][128], W_hh2^T fp32 [64][64],
//   W_ih1^T bf16 [28][128], W_ih2^T bf16 [128][64]  (bf16 to fit 160KiB LDS;
//   adds ~1e-3 abs error, threshold is 1.49e-2).
// h1 [64][132] f32, h2 [64][68] f32 (padded strides: keep 16B alignment for
// float4 ds_reads and break power-of-2 bank aliasing).
// Thread (hg=tid>>5, bl=tid&31): computes 16 h1-rows / 8 h2-rows for 2 batch
// elements. Weight reads are 2-address LDS broadcasts (free); h reads float4.

#define NBLK 256
#define NTHR 256

__device__ __forceinline__ unsigned short f2bf(float f) {
  unsigned int u = __float_as_uint(f);
  u = (u + 0x7FFFu + ((u >> 16) & 1u)) >> 16;   // round-to-nearest-even
  return (unsigned short)u;
}

__device__ __forceinline__ void unpk8(uint4 u, float (&w)[8]) {
  w[0] = __uint_as_float(u.x << 16);  w[1] = __uint_as_float(u.x & 0xffff0000u);
  w[2] = __uint_as_float(u.y << 16);  w[3] = __uint_as_float(u.y & 0xffff0000u);
  w[4] = __uint_as_float(u.z << 16);  w[5] = __uint_as_float(u.z & 0xffff0000u);
  w[6] = __uint_as_float(u.w << 16);  w[7] = __uint_as_float(u.w & 0xffff0000u);
}

__device__ __forceinline__ float tanh_fast(float v) {
  float e = __expf(2.0f * v);           // v_exp_f32 path; no overflow issues here
  return 1.0f - 2.0f / (e + 1.0f);      // == tanh(v); saturates correctly at +/-1
}

__global__ __launch_bounds__(NTHR, 1)
void rnn_fused(const float* __restrict__ x,
               const float* __restrict__ W_ih1, const float* __restrict__ W_hh1,
               const float* __restrict__ b_ih1, const float* __restrict__ b_hh1,
               const float* __restrict__ W_ih2, const float* __restrict__ W_hh2,
               const float* __restrict__ b_ih2, const float* __restrict__ b_hh2,
               const float* __restrict__ W_fc,  const float* __restrict__ b_fc,
               float* __restrict__ out)
{
  // LDS: 65536 + 16384 + 7168 + 16384 + 33792 + 17408 = 156672 B (<160 KiB)
  __shared__ float          W1T[128 * 128];     // W_hh1^T  [j][i]
  __shared__ float          W2T[64 * 64];       // W_hh2^T  [j][i]
  __shared__ unsigned short Wi1T[28 * 128];     // W_ih1^T  [j][i] bf16
  __shared__ unsigned short Wi2T[128 * 64];     // W_ih2^T  [j][i] bf16
  __shared__ float          h1s[64 * 132];      // stride 132 (528B, 16B-aligned)
  __shared__ float          h2s[64 * 68];       // stride 68  (272B, 16B-aligned)

  const int tid = threadIdx.x;
  const int hg  = tid >> 5;        // 0..7
  const int bl  = tid & 31;        // 0..31
  const int b0  = bl * 2, b1 = b0 + 1;
  const int blk = blockIdx.x;

  // ---- stage weights (transpose on the fly) ----
  for (int idx = tid; idx < 128 * 128; idx += NTHR) {
    int i = idx >> 7, j = idx & 127;
    W1T[j * 128 + i] = W_hh1[idx];
  }
  for (int idx = tid; idx < 64 * 64; idx += NTHR) {
    int i = idx >> 6, j = idx & 63;
    W2T[j * 64 + i] = W_hh2[idx];
  }
  for (int idx = tid; idx < 128 * 28; idx += NTHR) {
    int i = idx / 28, j = idx - i * 28;
    Wi1T[j * 128 + i] = f2bf(W_ih1[idx]);
  }
  for (int idx = tid; idx < 64 * 128; idx += NTHR) {
    int i = idx >> 7, j = idx & 127;
    Wi2T[j * 64 + i] = f2bf(W_ih2[idx]);
  }
  for (int idx = tid; idx < 64 * 132; idx += NTHR) h1s[idx] = 0.0f;
  for (int idx = tid; idx < 64 * 68;  idx += NTHR) h2s[idx] = 0.0f;

  // per-lane biases
  float b1r[16], b2r[8];
  #pragma unroll
  for (int ii = 0; ii < 16; ++ii) b1r[ii] = b_ih1[hg * 16 + ii] + b_hh1[hg * 16 + ii];
  #pragma unroll
  for (int ii = 0; ii < 8; ++ii)  b2r[ii] = b_ih2[hg * 8 + ii] + b_hh2[hg * 8 + ii];

  float accO0[10], accO1[10];
  #pragma unroll
  for (int c = 0; c < 10; ++c) { accO0[c] = 0.0f; accO1[c] = 0.0f; }

  const float* xr0 = x + (size_t)(blk * 64 + b0) * (28 * 28);
  const float* xr1 = x + (size_t)(blk * 64 + b1) * (28 * 28);

  __syncthreads();

  #pragma unroll 1
  for (int t = 0; t < 28; ++t) {
    // ================= layer 1 =================
    float a0[16], a1[16];
    #pragma unroll
    for (int ii = 0; ii < 16; ++ii) { a0[ii] = b1r[ii]; a1[ii] = b1r[ii]; }

    // x_t for both batch rows (global, L1-broadcast across hg groups)
    float xv0[28], xv1[28];
    #pragma unroll
    for (int m = 0; m < 7; ++m) {
      float4 v0 = *(const float4*)(xr0 + t * 28 + m * 4);
      float4 v1 = *(const float4*)(xr1 + t * 28 + m * 4);
      xv0[m*4+0] = v0.x; xv0[m*4+1] = v0.y; xv0[m*4+2] = v0.z; xv0[m*4+3] = v0.w;
      xv1[m*4+0] = v1.x; xv1[m*4+1] = v1.y; xv1[m*4+2] = v1.z; xv1[m*4+3] = v1.w;
    }

    // xw1: a += W_ih1^T[j][hg*16..+15] * x[j]
    for (int j = 0; j < 28; ++j) {
      const uint4* wp = (const uint4*)(Wi1T + j * 128 + hg * 16);
      float wA[8], wB[8];
      unpk8(wp[0], wA); unpk8(wp[1], wB);
      float xj0 = xv0[j], xj1 = xv1[j];
      #pragma unroll
      for (int ii = 0; ii < 8; ++ii) {
        a0[ii]     = fmaf(wA[ii], xj0, a0[ii]);
        a1[ii]     = fmaf(wA[ii], xj1, a1[ii]);
        a0[ii + 8] = fmaf(wB[ii], xj0, a0[ii + 8]);
        a1[ii + 8] = fmaf(wB[ii], xj1, a1[ii + 8]);
      }
    }

    // recurrent 1: a += W_hh1^T[j][...] * h1_old[b][j]
    if (t > 0) {
      for (int j = 0; j < 128; j += 4) {
        float4 hv0 = *(const float4*)(h1s + b0 * 132 + j);
        float4 hv1 = *(const float4*)(h1s + b1 * 132 + j);
        float h0a[4] = {hv0.x, hv0.y, hv0.z, hv0.w};
        float h1a[4] = {hv1.x, hv1.y, hv1.z, hv1.w};
        #pragma unroll
        for (int jj = 0; jj < 4; ++jj) {
          const float4* wp = (const float4*)(W1T + (j + jj) * 128 + hg * 16);
          float4 w0 = wp[0], w1 = wp[1], w2 = wp[2], w3 = wp[3];
          float w[16] = {w0.x, w0.y, w0.z, w0.w, w1.x, w1.y, w1.z, w1.w,
                         w2.x, w2.y, w2.z, w2.w, w3.x, w3.y, w3.z, w3.w};
          float hh0 = h0a[jj], hh1 = h1a[jj];
          #pragma unroll
          for (int ii = 0; ii < 16; ++ii) {
            a0[ii] = fmaf(w[ii], hh0, a0[ii]);
            a1[ii] = fmaf(w[ii], hh1, a1[ii]);
          }
        }
      }
    }

    #pragma unroll
    for (int ii = 0; ii < 16; ++ii) { a0[ii] = tanh_fast(a0[ii]); a1[ii] = tanh_fast(a1[ii]); }

    __syncthreads();   // A: all reads of h1_old complete
    #pragma unroll
    for (int ii = 0; ii < 16; ++ii) {
      h1s[b0 * 132 + hg * 16 + ii] = a0[ii];
      h1s[b1 * 132 + hg * 16 + ii] = a1[ii];
    }
    __syncthreads();   // B: h1_new visible

    // ================= layer 2 =================
    float c0[8], c1[8];
    #pragma unroll
    for (int ii = 0; ii < 8; ++ii) { c0[ii] = b2r[ii]; c1[ii] = b2r[ii]; }

    // xw2: c += W_ih2^T[j][hg*8..+7] * h1_new[b][j]
    for (int j = 0; j < 128; j += 4) {
      float4 hv0 = *(const float4*)(h1s + b0 * 132 + j);
      float4 hv1 = *(const float4*)(h1s + b1 * 132 + j);
      float h0a[4] = {hv0.x, hv0.y, hv0.z, hv0.w};
      float h1a[4] = {hv1.x, hv1.y, hv1.z, hv1.w};
      #pragma unroll
      for (int jj = 0; jj < 4; ++jj) {
        const uint4* wp = (const uint4*)(Wi2T + (j + jj) * 64 + hg * 8);
        float w[8];
        unpk8(wp[0], w);
        float hh0 = h0a[jj], hh1 = h1a[jj];
        #pragma unroll
        for (int ii = 0; ii < 8; ++ii) {
          c0[ii] = fmaf(w[ii], hh0, c0[ii]);
          c1[ii] = fmaf(w[ii], hh1, c1[ii]);
        }
      }
    }

    // recurrent 2: c += W_hh2^T[j][...] * h2_old[b][j]
    if (t > 0) {
      for (int j = 0; j < 64; j += 4) {
        float4 hv0 = *(const float4*)(h2s + b0 * 68 + j);
        float4 hv1 = *(const float4*)(h2s + b1 * 68 + j);
        float h0a[4] = {hv0.x, hv0.y, hv0.z, hv0.w};
        float h1a[4] = {hv1.x, hv1.y, hv1.z, hv1.w};
        #pragma unroll
        for (int jj = 0; jj < 4; ++jj) {
          const float4* wp = (const float4*)(W2T + (j + jj) * 64 + hg * 8);
          float4 w0 = wp[0], w1 = wp[1];
          float w[8] = {w0.x, w0.y, w0.z, w0.w, w1.x, w1.y, w1.z, w1.w};
          float hh0 = h0a[jj], hh1 = h1a[jj];
          #pragma unroll
          for (int ii = 0; ii < 8; ++ii) {
            c0[ii] = fmaf(w[ii], hh0, c0[ii]);
            c1[ii] = fmaf(w[ii], hh1, c1[ii]);
          }
        }
      }
    }

    #pragma unroll
    for (int ii = 0; ii < 8; ++ii) { c0[ii] = tanh_fast(c0[ii]); c1[ii] = tanh_fast(c1[ii]); }

    __syncthreads();   // C: all reads of h2_old complete
    #pragma unroll
    for (int ii = 0; ii < 8; ++ii) {
      h2s[b0 * 68 + hg * 8 + ii] = c0[ii];
      h2s[b1 * 68 + hg * 8 + ii] = c1[ii];
    }

    // FC accumulation straight from the h2_new registers (this lane computed
    // exactly the j-slice [hg*8, hg*8+8) it needs).
    {
      const float* wf = W_fc + t * 64 + hg * 8;
      #pragma unroll
      for (int c = 0; c < 10; ++c) {
        float4 wv0 = *(const float4*)(wf + (size_t)c * 1792);
        float4 wv1 = *(const float4*)(wf + (size_t)c * 1792 + 4);
        float w[8] = {wv0.x, wv0.y, wv0.z, wv0.w, wv1.x, wv1.y, wv1.z, wv1.w};
        #pragma unroll
        for (int jj = 0; jj < 8; ++jj) {
          accO0[c] = fmaf(w[jj], c0[jj], accO0[c]);
          accO1[c] = fmaf(w[jj], c1[jj], accO1[c]);
        }
      }
    }
    __syncthreads();   // D: h2_new visible for next step's recurrent reads
  }

  // ---- reduce FC partials across the 8 hg groups (overlay on h1s) ----
  float* red = h1s;    // needs 64*10*8 = 5120 floats; h1s has 8448
  #pragma unroll
  for (int c = 0; c < 10; ++c) {
    red[(b0 * 10 + c) * 8 + hg] = accO0[c];
    red[(b1 * 10 + c) * 8 + hg] = accO1[c];
  }
  __syncthreads();
  for (int idx = tid; idx < 640; idx += NTHR) {
    int b = idx / 10, c = idx - b * 10;
    float s = 0.0f;
    #pragma unroll
    for (int g = 0; g < 8; ++g) s += red[idx * 8 + g];
    out[(size_t)(blk * 64 + b) * 10 + c] = s + b_fc[c];
  }
}

extern "C" void kernel_launch(void* const* d_in, const int* in_sizes, int n_in,
                              void* d_out, int out_size, void* d_ws, size_t ws_size,
                              hipStream_t stream) {
  const float* x     = (const float*)d_in[0];
  const float* W_ih1 = (const float*)d_in[1];
  const float* W_hh1 = (const float*)d_in[2];
  const float* b_ih1 = (const float*)d_in[3];
  const float* b_hh1 = (const float*)d_in[4];
  const float* W_ih2 = (const float*)d_in[5];
  const float* W_hh2 = (const float*)d_in[6];
  const float* b_ih2 = (const float*)d_in[7];
  const float* b_hh2 = (const float*)d_in[8];
  const float* W_fc  = (const float*)d_in[9];
  const float* b_fc  = (const float*)d_in[10];

  rnn_fused<<<NBLK, NTHR, 0, stream>>>(x, W_ih1, W_hh1, b_ih1, b_hh1,
                                       W_ih2, W_hh2, b_ih2, b_hh2,
                                       W_fc, b_fc, (float*)d_out);
}

// Round 2
// 138.729 us; speedup vs baseline: 4.4010x; 4.4010x over previous
//
#include <hip/hip_runtime.h>
#include <hip/hip_bf16.h>
#include <type_traits>
#include <utility>

// Fused 2-layer Elman RNN + FC, MFMA version (MI355X / gfx950).
// B=16384, T=28, IN=28, H1=128, H2=64, NC=10.
// 256 blocks x 256 threads; block owns 64 batch rows end-to-end.
// All GEMMs on mfma_f32_16x16x32_bf16, M=batch. Waves split 2Mx2N.
// Weight B-fragments register-resident. h1/h2 stored in LDS as bf16 hi+lo
// pairs (error-compensated: 2 MFMAs per term) so recurrent bf16 rounding
// doesn't accumulate over the 28-step chain. Double-buffered state ->
// 2 barriers/step. XOR-16 column swizzle (per-lane constant) kills LDS
// bank conflicts on frag reads/writes.

#define NBLK 256
#define NTHR 256

typedef float  f32x4 __attribute__((ext_vector_type(4)));
typedef short  s16x8 __attribute__((ext_vector_type(8)));
typedef __bf16 b16x8 __attribute__((ext_vector_type(8)));

// Pick whichever operand vector type this ROCm's builtin accepts.
template <typename V, typename = void>
struct mfma_ok : std::false_type {};
template <typename V>
struct mfma_ok<V, std::void_t<decltype(__builtin_amdgcn_mfma_f32_16x16x32_bf16(
    std::declval<V>(), std::declval<V>(), std::declval<f32x4>(), 0, 0, 0))>>
    : std::true_type {};
using frag_t = std::conditional_t<mfma_ok<b16x8>::value, b16x8, s16x8>;

__device__ __forceinline__ f32x4 MFMA(frag_t a, frag_t b, f32x4 c) {
  return __builtin_amdgcn_mfma_f32_16x16x32_bf16(a, b, c, 0, 0, 0);
}

__device__ __forceinline__ unsigned short f2bf(float f) {
  unsigned int u = __float_as_uint(f);
  return (unsigned short)((u + 0x7FFFu + ((u >> 16) & 1u)) >> 16);  // RNE
}
__device__ __forceinline__ float bf2f(unsigned short h) {
  return __uint_as_float(((unsigned int)h) << 16);
}
__device__ __forceinline__ frag_t bitfrag(s16x8 s) {
  return __builtin_bit_cast(frag_t, s);
}

// 8 consecutive f32 -> bf16 frag (B-operand: 8 k's for this lane's column)
__device__ __forceinline__ frag_t ldw8(const float* p) {
  float4 a = *(const float4*)(p);
  float4 b = *(const float4*)(p + 4);
  s16x8 r;
  r[0]=(short)f2bf(a.x); r[1]=(short)f2bf(a.y); r[2]=(short)f2bf(a.z); r[3]=(short)f2bf(a.w);
  r[4]=(short)f2bf(b.x); r[5]=(short)f2bf(b.y); r[6]=(short)f2bf(b.z); r[7]=(short)f2bf(b.w);
  return bitfrag(r);
}
__device__ __forceinline__ frag_t ldw4z(const float* p) {  // 4 valid + 4 zero (K-pad)
  float4 a = *(const float4*)(p);
  s16x8 r;
  r[0]=(short)f2bf(a.x); r[1]=(short)f2bf(a.y); r[2]=(short)f2bf(a.z); r[3]=(short)f2bf(a.w);
  r[4]=0; r[5]=0; r[6]=0; r[7]=0;
  return bitfrag(r);
}

__device__ __forceinline__ float tanh_fast(float v) {
  float e = __expf(2.0f * v);
  return 1.0f - 2.0f / (e + 1.0f);
}

__global__ __launch_bounds__(NTHR, 1)
void rnn_mfma(const float* __restrict__ x,
              const float* __restrict__ W_ih1, const float* __restrict__ W_hh1,
              const float* __restrict__ b_ih1, const float* __restrict__ b_hh1,
              const float* __restrict__ W_ih2, const float* __restrict__ W_hh2,
              const float* __restrict__ b_ih2, const float* __restrict__ b_hh2,
              const float* __restrict__ W_fc,  const float* __restrict__ b_fc,
              float* __restrict__ out)
{
  // LDS: 69,632 + 36,864 + 36,000 = 142,496 B  (< 160 KiB)
  __shared__ alignas(16) unsigned short h1hi[2][64][136];
  __shared__ alignas(16) unsigned short h1lo[2][64][136];
  __shared__ alignas(16) unsigned short h2hi[2][64][72];
  __shared__ alignas(16) unsigned short h2lo[2][64][72];
  __shared__ alignas(16) unsigned short wfc[10][1800];

  const int tid  = threadIdx.x;
  const int w    = tid >> 6;          // wave 0..3
  const int lane = tid & 63;
  const int li   = lane & 15;
  const int g    = lane >> 4;         // 0..3 (k-group / row-group)
  const int wm   = w >> 1;            // M half: batch rows [wm*32, wm*32+32)
  const int wn   = w & 1;             // N half
  const int blk  = blockIdx.x;
  // column swizzle: element (row,col) stored at col ^ (((row>>3)&1)<<4).
  // For A-frag reads row = base16*m + li  -> swizzle = f(lane bit3).
  // For D-frag writes row = base16 + g*4 + r -> swizzle = f(lane bit5).
  const int swr  = ((lane >> 3) & 1) << 4;
  const int swv  = ((lane >> 5) & 1) << 4;

  // ---- stage W_fc -> LDS bf16 [10][1800] (pad cols never read) ----
  for (int idx = tid; idx < 10 * 1792; idx += NTHR) {
    int r = idx / 1792, c = idx - r * 1792;
    wfc[r][c] = f2bf(W_fc[idx]);
  }

  // ---- register-resident weight B-fragments ----
  // frag (kt,nt): lane holds W^T[k0+e][n] = W[n][k0+e]; n = base+nt*16+li, k0 = kt*32+g*8
  frag_t wB1[4][4];                    // W_hh1^T  K=128, N-slice 64 @ wn*64
  #pragma unroll
  for (int kt = 0; kt < 4; ++kt)
    #pragma unroll
    for (int nt = 0; nt < 4; ++nt) {
      int n = wn * 64 + nt * 16 + li;
      wB1[kt][nt] = ldw8(W_hh1 + n * 128 + kt * 32 + g * 8);
    }
  frag_t wBi1[4];                      // W_ih1^T  K=28 (pad 32), N-slice 64
  #pragma unroll
  for (int nt = 0; nt < 4; ++nt) {
    int n = wn * 64 + nt * 16 + li;
    wBi1[nt] = (g < 3) ? ldw8(W_ih1 + n * 28 + g * 8)
                       : ldw4z(W_ih1 + n * 28 + 24);
  }
  frag_t wBi2[4][2];                   // W_ih2^T  K=128, N-slice 32 @ wn*32
  #pragma unroll
  for (int kt = 0; kt < 4; ++kt)
    #pragma unroll
    for (int nt = 0; nt < 2; ++nt) {
      int n = wn * 32 + nt * 16 + li;
      wBi2[kt][nt] = ldw8(W_ih2 + n * 128 + kt * 32 + g * 8);
    }
  frag_t wB2[2][2];                    // W_hh2^T  K=64, N-slice 32
  #pragma unroll
  for (int kt = 0; kt < 2; ++kt)
    #pragma unroll
    for (int nt = 0; nt < 2; ++nt) {
      int n = wn * 32 + nt * 16 + li;
      wB2[kt][nt] = ldw8(W_hh2 + n * 64 + kt * 32 + g * 8);
    }

  // biases (splat over D-frag rows; depend on col = l&15 only)
  float b1v[4], b2v[2];
  #pragma unroll
  for (int nt = 0; nt < 4; ++nt) { int c = wn*64 + nt*16 + li; b1v[nt] = b_ih1[c] + b_hh1[c]; }
  #pragma unroll
  for (int nt = 0; nt < 2; ++nt) { int c = wn*32 + nt*16 + li; b2v[nt] = b_ih2[c] + b_hh2[c]; }

  // x prefetch for t=0: A-frag source, lane reads x[row][g*8 .. g*8+7]
  const float* xbase = x + (size_t)(blk * 64) * 784;
  float4 xfa[2], xfb[2];
  #pragma unroll
  for (int mt = 0; mt < 2; ++mt) {
    const float* p = xbase + (wm * 32 + mt * 16 + li) * 784 + g * 8;
    xfa[mt] = *(const float4*)(p);
    xfb[mt] = (g < 3) ? *(const float4*)(p + 4) : float4{0.f, 0.f, 0.f, 0.f};
  }

  f32x4 fca = {0.f, 0.f, 0.f, 0.f};

  __syncthreads();   // wfc staged

  #pragma unroll 1
  for (int t = 0; t < 28; ++t) {
    const int cb = t & 1, pb = cb ^ 1;

    // convert prefetched x to A-frags; then issue prefetch for t+1
    frag_t xA[2];
    #pragma unroll
    for (int mt = 0; mt < 2; ++mt) {
      s16x8 r;
      r[0]=(short)f2bf(xfa[mt].x); r[1]=(short)f2bf(xfa[mt].y);
      r[2]=(short)f2bf(xfa[mt].z); r[3]=(short)f2bf(xfa[mt].w);
      r[4]=(short)f2bf(xfb[mt].x); r[5]=(short)f2bf(xfb[mt].y);
      r[6]=(short)f2bf(xfb[mt].z); r[7]=(short)f2bf(xfb[mt].w);
      xA[mt] = bitfrag(r);
    }
    {
      const int tn = (t < 27) ? t + 1 : 27;
      #pragma unroll
      for (int mt = 0; mt < 2; ++mt) {
        const float* p = xbase + (wm * 32 + mt * 16 + li) * 784 + tn * 28 + g * 8;
        xfa[mt] = *(const float4*)(p);
        if (g < 3) xfb[mt] = *(const float4*)(p + 4);   // g==3 tail stays zero
      }
    }

    // ======== layer 1: pre1 = x W_ih1^T + h1(t-1) W_hh1^T + b ========
    f32x4 acc1[2][4];
    #pragma unroll
    for (int mt = 0; mt < 2; ++mt)
      #pragma unroll
      for (int nt = 0; nt < 4; ++nt)
        acc1[mt][nt] = f32x4{b1v[nt], b1v[nt], b1v[nt], b1v[nt]};

    #pragma unroll
    for (int mt = 0; mt < 2; ++mt)
      #pragma unroll
      for (int nt = 0; nt < 4; ++nt)
        acc1[mt][nt] = MFMA(xA[mt], wBi1[nt], acc1[mt][nt]);

    if (t > 0) {
      #pragma unroll
      for (int kt = 0; kt < 4; ++kt) {
        frag_t ahi[2], alo[2];
        #pragma unroll
        for (int mt = 0; mt < 2; ++mt) {
          const int row = wm * 32 + mt * 16 + li;
          const int k0  = (kt * 32 + g * 8) ^ swr;
          ahi[mt] = *(const frag_t*)&h1hi[pb][row][k0];
          alo[mt] = *(const frag_t*)&h1lo[pb][row][k0];
        }
        #pragma unroll
        for (int mt = 0; mt < 2; ++mt)
          #pragma unroll
          for (int nt = 0; nt < 4; ++nt) {
            acc1[mt][nt] = MFMA(ahi[mt], wB1[kt][nt], acc1[mt][nt]);
            acc1[mt][nt] = MFMA(alo[mt], wB1[kt][nt], acc1[mt][nt]);
          }
      }
    }

    // tanh -> hi/lo -> h1[cb]
    #pragma unroll
    for (int mt = 0; mt < 2; ++mt)
      #pragma unroll
      for (int nt = 0; nt < 4; ++nt) {
        const int colsw = ((wn * 64 + nt * 16) ^ swv) + li;
        #pragma unroll
        for (int r = 0; r < 4; ++r) {
          const int row = wm * 32 + mt * 16 + g * 4 + r;
          float f = tanh_fast(acc1[mt][nt][r]);
          unsigned short hi = f2bf(f);
          unsigned short lo = f2bf(f - bf2f(hi));
          h1hi[cb][row][colsw] = hi;
          h1lo[cb][row][colsw] = lo;
        }
      }

    __syncthreads();   // B1: h1(t) visible

    // ======== layer 2: pre2 = h1(t) W_ih2^T + h2(t-1) W_hh2^T + b ========
    f32x4 acc2[2][2];
    #pragma unroll
    for (int mt = 0; mt < 2; ++mt)
      #pragma unroll
      for (int nt = 0; nt < 2; ++nt)
        acc2[mt][nt] = f32x4{b2v[nt], b2v[nt], b2v[nt], b2v[nt]};

    #pragma unroll
    for (int kt = 0; kt < 4; ++kt) {
      frag_t ahi[2], alo[2];
      #pragma unroll
      for (int mt = 0; mt < 2; ++mt) {
        const int row = wm * 32 + mt * 16 + li;
        const int k0  = (kt * 32 + g * 8) ^ swr;
        ahi[mt] = *(const frag_t*)&h1hi[cb][row][k0];
        alo[mt] = *(const frag_t*)&h1lo[cb][row][k0];
      }
      #pragma unroll
      for (int mt = 0; mt < 2; ++mt)
        #pragma unroll
        for (int nt = 0; nt < 2; ++nt) {
          acc2[mt][nt] = MFMA(ahi[mt], wBi2[kt][nt], acc2[mt][nt]);
          acc2[mt][nt] = MFMA(alo[mt], wBi2[kt][nt], acc2[mt][nt]);
        }
    }

    if (t > 0) {
      #pragma unroll
      for (int kt = 0; kt < 2; ++kt) {
        frag_t ahi[2], alo[2];
        #pragma unroll
        for (int mt = 0; mt < 2; ++mt) {
          const int row = wm * 32 + mt * 16 + li;
          const int k0  = (kt * 32 + g * 8) ^ swr;
          ahi[mt] = *(const frag_t*)&h2hi[pb][row][k0];
          alo[mt] = *(const frag_t*)&h2lo[pb][row][k0];
        }
        #pragma unroll
        for (int mt = 0; mt < 2; ++mt)
          #pragma unroll
          for (int nt = 0; nt < 2; ++nt) {
            acc2[mt][nt] = MFMA(ahi[mt], wB2[kt][nt], acc2[mt][nt]);
            acc2[mt][nt] = MFMA(alo[mt], wB2[kt][nt], acc2[mt][nt]);
          }
      }
    }

    // tanh -> hi/lo -> h2[cb]
    #pragma unroll
    for (int mt = 0; mt < 2; ++mt)
      #pragma unroll
      for (int nt = 0; nt < 2; ++nt) {
        const int colsw = ((wn * 32 + nt * 16) ^ swv) + li;
        #pragma unroll
        for (int r = 0; r < 4; ++r) {
          const int row = wm * 32 + mt * 16 + g * 4 + r;
          float f = tanh_fast(acc2[mt][nt][r]);
          unsigned short hi = f2bf(f);
          unsigned short lo = f2bf(f - bf2f(hi));
          h2hi[cb][row][colsw] = hi;
          h2lo[cb][row][colsw] = lo;
        }
      }

    __syncthreads();   // B2: h2(t) visible

    // ======== FC accumulation: fca += h2(t) . W_fc[:, t*64 .. +64)^T ========
    {
      const int cls = (li < 10) ? li : 0;   // lanes 10..15 broadcast row 0; cols 10..15 unused
      const int row = w * 16 + li;          // wave w owns batch tile w
      #pragma unroll
      for (int kt = 0; kt < 2; ++kt) {
        const int k0 = (kt * 32 + g * 8) ^ swr;
        frag_t ahi = *(const frag_t*)&h2hi[cb][row][k0];
        frag_t alo = *(const frag_t*)&h2lo[cb][row][k0];
        frag_t bfc = *(const frag_t*)&wfc[cls][t * 64 + kt * 32 + g * 8];
        fca = MFMA(ahi, bfc, fca);
        fca = MFMA(alo, bfc, fca);
      }
    }
  }

  // ---- epilogue: D-frag (row = g*4+r within tile, col = li) -> global ----
  if (li < 10) {
    const float bv = b_fc[li];
    #pragma unroll
    for (int r = 0; r < 4; ++r) {
      const int b = w * 16 + g * 4 + r;
      out[(size_t)(blk * 64 + b) * 10 + li] = fca[r] + bv;
    }
  }
}

extern "C" void kernel_launch(void* const* d_in, const int* in_sizes, int n_in,
                              void* d_out, int out_size, void* d_ws, size_t ws_size,
                              hipStream_t stream) {
  const float* x     = (const float*)d_in[0];
  const float* W_ih1 = (const float*)d_in[1];
  const float* W_hh1 = (const float*)d_in[2];
  const float* b_ih1 = (const float*)d_in[3];
  const float* b_hh1 = (const float*)d_in[4];
  const float* W_ih2 = (const float*)d_in[5];
  const float* W_hh2 = (const float*)d_in[6];
  const float* b_ih2 = (const float*)d_in[7];
  const float* b_hh2 = (const float*)d_in[8];
  const float* W_fc  = (const float*)d_in[9];
  const float* b_fc  = (const float*)d_in[10];

  rnn_mfma<<<NBLK, NTHR, 0, stream>>>(x, W_ih1, W_hh1, b_ih1, b_hh1,
                                      W_ih2, W_hh2, b_ih2, b_hh2,
                                      W_fc, b_fc, (float*)d_out);
}

// Round 3
// 97.534 us; speedup vs baseline: 6.2598x; 1.4224x over previous
//
#include <hip/hip_runtime.h>
#include <hip/hip_bf16.h>
#include <type_traits>
#include <utility>

// Fused 2-layer Elman RNN + FC, round 3: occupancy-first.
// B=16384, T=28, IN=28, H1=128, H2=64, NC=10.
// 1024 blocks x 256 thr; block owns 16 batch rows. Waves N-split-4:
// wave wn owns H1-cols [wn*32,+32), H2-cols [wn*16,+16). Weight B-frags in
// registers (64 VGPR). Plain bf16 state in LDS (15.4 KB/block, XOR-16
// swizzle), double-buffered, 2 barriers/step. __launch_bounds__(256,4)
// -> target 4 blocks/CU = 16 waves/CU for latency hiding.

#define NBLK 1024
#define NTHR 256

typedef float  f32x4 __attribute__((ext_vector_type(4)));
typedef short  s16x8 __attribute__((ext_vector_type(8)));
typedef __bf16 b16x8 __attribute__((ext_vector_type(8)));

template <typename V, typename = void> struct mfma_ok : std::false_type {};
template <typename V>
struct mfma_ok<V, std::void_t<decltype(__builtin_amdgcn_mfma_f32_16x16x32_bf16(
    std::declval<V>(), std::declval<V>(), std::declval<f32x4>(), 0, 0, 0))>>
    : std::true_type {};
using frag_t = std::conditional_t<mfma_ok<b16x8>::value, b16x8, s16x8>;

__device__ __forceinline__ f32x4 MFMA(frag_t a, frag_t b, f32x4 c) {
  return __builtin_amdgcn_mfma_f32_16x16x32_bf16(a, b, c, 0, 0, 0);
}

__device__ __forceinline__ unsigned short f2bf(float f) {
  unsigned int u = __float_as_uint(f);
  return (unsigned short)((u + 0x7FFFu + ((u >> 16) & 1u)) >> 16);  // RNE
}
__device__ __forceinline__ frag_t bitfrag(s16x8 s) {
  return __builtin_bit_cast(frag_t, s);
}
__device__ __forceinline__ frag_t pack8(float4 a, float4 b) {
  s16x8 r;
  r[0]=(short)f2bf(a.x); r[1]=(short)f2bf(a.y); r[2]=(short)f2bf(a.z); r[3]=(short)f2bf(a.w);
  r[4]=(short)f2bf(b.x); r[5]=(short)f2bf(b.y); r[6]=(short)f2bf(b.z); r[7]=(short)f2bf(b.w);
  return bitfrag(r);
}
__device__ __forceinline__ frag_t ldw8(const float* p) {
  float4 a = *(const float4*)(p);
  float4 b = *(const float4*)(p + 4);
  return pack8(a, b);
}
__device__ __forceinline__ frag_t ldw4z(const float* p) {  // 4 valid + 4 zero
  float4 a = *(const float4*)(p);
  return pack8(a, float4{0.f, 0.f, 0.f, 0.f});
}
__device__ __forceinline__ float tanh_fast(float v) {
  float e = __expf(2.0f * v);
  return 1.0f - 2.0f / (e + 1.0f);
}

__global__ __launch_bounds__(NTHR, 4)
void rnn_mfma3(const float* __restrict__ x,
               const float* __restrict__ W_ih1, const float* __restrict__ W_hh1,
               const float* __restrict__ b_ih1, const float* __restrict__ b_hh1,
               const float* __restrict__ W_ih2, const float* __restrict__ W_hh2,
               const float* __restrict__ b_ih2, const float* __restrict__ b_hh2,
               const float* __restrict__ W_fc,  const float* __restrict__ b_fc,
               float* __restrict__ out)
{
  // LDS: 8704 + 4608 + 2048 = 15,360 B
  __shared__ alignas(16) unsigned short h1s[2][16][136];
  __shared__ alignas(16) unsigned short h2s[2][16][72];
  __shared__ alignas(16) float red[2][16][16];

  const int tid  = threadIdx.x;
  const int wn   = tid >> 6;          // wave = N-split index 0..3
  const int lane = tid & 63;
  const int li   = lane & 15;         // A-row (batch) / D-col
  const int g    = lane >> 4;         // 0..3 k-group / D-row-group
  const int blk  = blockIdx.x;
  // XOR-16 column swizzle: (row,col) stored at col ^ (((row>>3)&1)<<4)
  const int swr  = ((li >> 3) & 1) << 4;          // reads: row = li
  const int swv  = ((g >> 1) & 1) << 4;           // writes: row = g*4+r

  // ---- register-resident weight B-frags (bf16) ----
  // frag (kt,nt): lane holds W^T[k][n] = W[n][k], n = base+nt*16+li, k = kt*32+g*8..+7
  const int n1 = wn * 32 + li;        // +nt*16
  const int n2 = wn * 16 + li;
  frag_t wB1[4][2], wBi1[2], wBi2[4], wB2[2];
  #pragma unroll
  for (int kt = 0; kt < 4; ++kt)
    #pragma unroll
    for (int nt = 0; nt < 2; ++nt)
      wB1[kt][nt] = ldw8(W_hh1 + (n1 + nt * 16) * 128 + kt * 32 + g * 8);
  #pragma unroll
  for (int nt = 0; nt < 2; ++nt)
    wBi1[nt] = (g < 3) ? ldw8(W_ih1 + (n1 + nt * 16) * 28 + g * 8)
                       : ldw4z(W_ih1 + (n1 + nt * 16) * 28 + 24);
  #pragma unroll
  for (int kt = 0; kt < 4; ++kt)
    wBi2[kt] = ldw8(W_ih2 + n2 * 128 + kt * 32 + g * 8);
  #pragma unroll
  for (int kt = 0; kt < 2; ++kt)
    wB2[kt] = ldw8(W_hh2 + n2 * 64 + kt * 32 + g * 8);

  float b1v[2];
  b1v[0] = b_ih1[n1] + b_hh1[n1];
  b1v[1] = b_ih1[n1 + 16] + b_hh1[n1 + 16];
  const float b2v = b_ih2[n2] + b_hh2[n2];

  const float* xrow = x + (size_t)(blk * 16 + li) * 784 + g * 8;
  const int   cls  = (li < 10) ? li : 0;
  const float* wfp = W_fc + (size_t)cls * 1792 + (wn & 1) * 32 + g * 8;

  f32x4 fca = {0.f, 0.f, 0.f, 0.f};

  #pragma unroll 1
  for (int t = 0; t < 28; ++t) {
    const int cb = t & 1, pb = cb ^ 1;

    // ---- layer 1 ----
    // issue x loads first (hidden under the recurrent ds_reads + MFMAs)
    float4 xa = *(const float4*)(xrow + t * 28);
    float4 xb = (g < 3) ? *(const float4*)(xrow + t * 28 + 4)
                        : float4{0.f, 0.f, 0.f, 0.f};

    f32x4 acc1[2];
    acc1[0] = f32x4{b1v[0], b1v[0], b1v[0], b1v[0]};
    acc1[1] = f32x4{b1v[1], b1v[1], b1v[1], b1v[1]};

    if (t > 0) {
      #pragma unroll
      for (int kt = 0; kt < 4; ++kt) {
        frag_t a = *(const frag_t*)&h1s[pb][li][(kt * 32 + g * 8) ^ swr];
        acc1[0] = MFMA(a, wB1[kt][0], acc1[0]);
        acc1[1] = MFMA(a, wB1[kt][1], acc1[1]);
      }
    }
    {
      frag_t xA = pack8(xa, xb);
      acc1[0] = MFMA(xA, wBi1[0], acc1[0]);
      acc1[1] = MFMA(xA, wBi1[1], acc1[1]);
    }

    #pragma unroll
    for (int nt = 0; nt < 2; ++nt) {
      const int colsw = ((wn * 32 + nt * 16) ^ swv) + li;
      #pragma unroll
      for (int r = 0; r < 4; ++r)
        h1s[cb][g * 4 + r][colsw] = f2bf(tanh_fast(acc1[nt][r]));
    }

    __syncthreads();   // B1: h1(t) visible

    // ---- layer 2 ----
    f32x4 acc2 = f32x4{b2v, b2v, b2v, b2v};
    #pragma unroll
    for (int kt = 0; kt < 4; ++kt) {
      frag_t a = *(const frag_t*)&h1s[cb][li][(kt * 32 + g * 8) ^ swr];
      acc2 = MFMA(a, wBi2[kt], acc2);
    }
    if (t > 0) {
      #pragma unroll
      for (int kt = 0; kt < 2; ++kt) {
        frag_t a = *(const frag_t*)&h2s[pb][li][(kt * 32 + g * 8) ^ swr];
        acc2 = MFMA(a, wB2[kt], acc2);
      }
    }
    {
      const int colsw = ((wn * 16) ^ swv) + li;
      #pragma unroll
      for (int r = 0; r < 4; ++r)
        h2s[cb][g * 4 + r][colsw] = f2bf(tanh_fast(acc2[r]));
    }

    __syncthreads();   // B2: h2(t) visible

    // ---- FC accumulation (waves 0,1 split K=64) ----
    if (wn < 2) {
      frag_t a  = *(const frag_t*)&h2s[cb][li][(wn * 32 + g * 8) ^ swr];
      frag_t bf = ldw8(wfp + t * 64);
      fca = MFMA(a, bf, fca);
    }
  }

  // ---- epilogue: 2-way K-reduce + bias + store ----
  if (wn < 2) {
    #pragma unroll
    for (int r = 0; r < 4; ++r)
      red[wn][g * 4 + r][li] = fca[r];
  }
  __syncthreads();
  if (tid < 160) {
    const int b = tid / 10, c = tid - b * 10;
    out[(size_t)(blk * 16 + b) * 10 + c] = red[0][b][c] + red[1][b][c] + b_fc[c];
  }
}

extern "C" void kernel_launch(void* const* d_in, const int* in_sizes, int n_in,
                              void* d_out, int out_size, void* d_ws, size_t ws_size,
                              hipStream_t stream) {
  const float* x     = (const float*)d_in[0];
  const float* W_ih1 = (const float*)d_in[1];
  const float* W_hh1 = (const float*)d_in[2];
  const float* b_ih1 = (const float*)d_in[3];
  const float* b_hh1 = (const float*)d_in[4];
  const float* W_ih2 = (const float*)d_in[5];
  const float* W_hh2 = (const float*)d_in[6];
  const float* b_ih2 = (const float*)d_in[7];
  const float* b_hh2 = (const float*)d_in[8];
  const float* W_fc  = (const float*)d_in[9];
  const float* b_fc  = (const float*)d_in[10];

  rnn_mfma3<<<NBLK, NTHR, 0, stream>>>(x, W_ih1, W_hh1, b_ih1, b_hh1,
                                       W_ih2, W_hh2, b_ih2, b_hh2,
                                       W_fc, b_fc, (float*)d_out);
}